// Round 3
// baseline (558.676 us; speedup 1.0000x reference)
//
#include <hip/hip_runtime.h>
#include <stdint.h>

#define NB 32
#define NS 2048
#define NE 1024   // ENC
#define ND 1024   // DEC
#define NA 1024   // ATT
#define MROWS (NB * NS)   // 65536

typedef float f32x4 __attribute__((ext_vector_type(4)));
typedef __bf16 bf16x8 __attribute__((ext_vector_type(8)));
typedef int i32x4 __attribute__((ext_vector_type(4)));
typedef unsigned int u32x2 __attribute__((ext_vector_type(2)));
typedef unsigned short u16x4 __attribute__((ext_vector_type(4)));

typedef __attribute__((address_space(3))) unsigned int lds_u32;
typedef __attribute__((address_space(1))) unsigned int glb_u32;

__device__ __forceinline__ unsigned short f32_bf16(float x){
  unsigned int u = __float_as_uint(x);
  unsigned int r = (u + 0x7fffu + ((u >> 16) & 1u)) >> 16;
  return (unsigned short)r;
}
__device__ __forceinline__ float bf16_f32(unsigned short h){
  return __uint_as_float(((unsigned int)h) << 16);
}
__device__ __forceinline__ float tanh_fast(float x){
  float ax = fabsf(x);
  float e = __expf(-2.0f * ax);
  float t = (1.0f - e) * __builtin_amdgcn_rcpf(1.0f + e);
  return x < 0.0f ? -t : t;
}
__device__ __forceinline__ void gload_lds16(const void* g, void* l){
  __builtin_amdgcn_global_load_lds((const glb_u32*)g, (lds_u32*)l, 16, 0, 0);
}

// ---------------- kernel 0: split W_e2a (f32) -> hi/lo bf16 ----------------
__global__ __launch_bounds__(256) void split_w_kernel(
    const float* __restrict__ W, unsigned short* __restrict__ hi,
    unsigned short* __restrict__ lo)
{
  int i = (blockIdx.x * 256 + threadIdx.x) * 4;
  f32x4 w = *reinterpret_cast<const f32x4*>(W + i);
  u16x4 h, l;
  #pragma unroll
  for (int j = 0; j < 4; ++j){
    unsigned short hh = f32_bf16(w[j]);
    h[j] = hh;
    l[j] = f32_bf16(w[j] - bf16_f32(hh));
  }
  *reinterpret_cast<u16x4*>(hi + i) = h;
  *reinterpret_cast<u16x4*>(lo + i) = l;
}

// ---------------- kernel 0b: split keys (f32) -> hi/lo bf16 ----------------
__global__ __launch_bounds__(256) void split_keys_kernel(
    const float* __restrict__ K, unsigned short* __restrict__ hi,
    unsigned short* __restrict__ lo)
{
  size_t i = ((size_t)blockIdx.x * 256 + threadIdx.x) * 8;
  f32x4 a = *reinterpret_cast<const f32x4*>(K + i);
  f32x4 b = *reinterpret_cast<const f32x4*>(K + i + 4);
  u16x4 h0, h1, l0, l1;
  #pragma unroll
  for (int j = 0; j < 4; ++j){
    unsigned short hh = f32_bf16(a[j]);
    h0[j] = hh; l0[j] = f32_bf16(a[j] - bf16_f32(hh));
    unsigned short hb = f32_bf16(b[j]);
    h1[j] = hb; l1[j] = f32_bf16(b[j] - bf16_f32(hb));
  }
  *reinterpret_cast<u16x4*>(hi + i)     = h0;
  *reinterpret_cast<u16x4*>(hi + i + 4) = h1;
  *reinterpret_cast<u16x4*>(lo + i)     = l0;
  *reinterpret_cast<u16x4*>(lo + i + 4) = l1;
}

// ---------------- kernel 1: V[b][a] = sum_d q[b][d]*W_d2a[a][d] ------------
__global__ __launch_bounds__(256) void v_kernel(
    const float* __restrict__ q, const float* __restrict__ Wd,
    float* __restrict__ V)
{
  int gw = blockIdx.x * 4 + (threadIdx.x >> 6);
  int l = threadIdx.x & 63;
  int b = gw >> 10, a = gw & 1023;
  const float* qp = q + b * ND;
  const float* wp = Wd + (size_t)a * ND;
  float s = 0.0f;
  #pragma unroll
  for (int c = 0; c < 4; ++c){
    int off = c * 256 + l * 4;
    f32x4 q4 = *reinterpret_cast<const f32x4*>(qp + off);
    f32x4 w4 = *reinterpret_cast<const f32x4*>(wp + off);
    s += q4[0]*w4[0] + q4[1]*w4[1] + q4[2]*w4[2] + q4[3]*w4[3];
  }
  #pragma unroll
  for (int off = 1; off < 64; off <<= 1) s += __shfl_xor(s, off, 64);
  if (l == 0) V[gw] = s;
}

// ---------------- kernel 2 (BIG): 256x256 8-wave counted-vmcnt GEMM --------
// Grid 1024 = 256 M-tiles (BM=256) x 4 N-chunks (BN=256). 512 thr = 8 waves
// (2M x 4N), per-wave 128x64 output, acc[8][4]. BK=32, double-buffered LDS
// 128 KB (A-hi/A-lo/B-hi/B-lo x 16KB x 2buf). Both operands staged with
// global_load_lds + inverse-swizzled source; counted vmcnt(8) keeps the
// prefetch in flight across all phase barriers; 4 phases x 24 MFMA w/ setprio.
__global__ __launch_bounds__(512, 2) void score_big_kernel(
    const unsigned short* __restrict__ Khi,
    const unsigned short* __restrict__ Klo,
    const unsigned short* __restrict__ Whi,
    const unsigned short* __restrict__ Wlo,
    const float* __restrict__ Vb,
    const float* __restrict__ vw,
    float* __restrict__ e_part)
{
  __shared__ __align__(16) unsigned short sh[65536];  // 128 KB
  __shared__ float ebuf[4][256];

  const int t = threadIdx.x;
  const int w = t >> 6, l = t & 63;
  const int l15 = l & 15, lg = l >> 4;
  const int wr = w >> 2, wc = w & 3;

  // XCD-bijective swizzle: the 4 N-chunks of one M-tile land on one XCD.
  const int orig = blockIdx.x;
  const int xcd = orig & 7;
  const int s0 = orig >> 3;
  const int mtile = ((s0 >> 2) << 3) | xcd;   // bijective over [0,256)
  const int nchunk = s0 & 3;
  const int row0 = mtile << 8;
  const int nb0 = nchunk << 8;
  const int bb = row0 >> 11;

  // staging offsets (kt-invariant). chunk = w*2+p owns LDS bytes [chunk*1K,+1K)
  size_t aoff[2], boff[2];
  int ldsoff[2];
  #pragma unroll
  for (int p = 0; p < 2; ++p){
    int chunk = (w << 1) + p;
    int row = (chunk << 4) + (l >> 2);
    int blk = (l & 3) ^ (row & 3);            // inverse swizzle on source
    aoff[p] = (size_t)(row0 + row) * NE + (blk << 3);
    boff[p] = (size_t)(nb0 + row) * NE + (blk << 3);
    ldsoff[p] = chunk << 9;                    // ushort index
  }

  // ds_read offsets (kt-invariant), XOR-swizzled
  int aidx[8], bidx[4];
  #pragma unroll
  for (int mf = 0; mf < 8; ++mf){
    int row = (wr << 7) + (mf << 4) + l15;
    aidx[mf] = (row << 5) + ((lg ^ (row & 3)) << 3);
  }
  #pragma unroll
  for (int nf = 0; nf < 4; ++nf){
    int row = (wc << 6) + (nf << 4) + l15;
    bidx[nf] = (row << 5) + ((lg ^ (row & 3)) << 3);
  }

  f32x4 acc[8][4];
  #pragma unroll
  for (int mf = 0; mf < 8; ++mf)
    #pragma unroll
    for (int nf = 0; nf < 4; ++nf)
      acc[mf][nf] = (f32x4)0.0f;

  // prologue: stage kt=0 -> buf0 (8 gload_lds per thread)
  #pragma unroll
  for (int p = 0; p < 2; ++p){
    unsigned short* lb = &sh[ldsoff[p]];
    gload_lds16(Khi + aoff[p], lb);
    gload_lds16(Klo + aoff[p], lb + 8192);
    gload_lds16(Whi + boff[p], lb + 16384);
    gload_lds16(Wlo + boff[p], lb + 24576);
  }

  for (int kt = 0; kt < 32; ++kt){
    const int cur = (kt & 1) << 15;
    if (kt < 31){
      const int nxt = ((kt + 1) & 1) << 15;
      const int kc = (kt + 1) << 5;
      #pragma unroll
      for (int p = 0; p < 2; ++p){
        unsigned short* lb = &sh[nxt + ldsoff[p]];
        gload_lds16(Khi + aoff[p] + kc, lb);
        gload_lds16(Klo + aoff[p] + kc, lb + 8192);
        gload_lds16(Whi + boff[p] + kc, lb + 16384);
        gload_lds16(Wlo + boff[p] + kc, lb + 24576);
      }
      asm volatile("s_waitcnt vmcnt(8)" ::: "memory");  // wait kt's 8; keep kt+1's in flight
    } else {
      asm volatile("s_waitcnt vmcnt(0)" ::: "memory");
    }
    __builtin_amdgcn_s_barrier();

    const unsigned short* L = &sh[cur];
    bf16x8 bh[4], bl4[4];
    #pragma unroll
    for (int p = 0; p < 4; ++p){
      bf16x8 ah[2], al[2];
      #pragma unroll
      for (int j = 0; j < 2; ++j){
        ah[j] = __builtin_bit_cast(bf16x8, *reinterpret_cast<const i32x4*>(&L[aidx[2*p+j]]));
        al[j] = __builtin_bit_cast(bf16x8, *reinterpret_cast<const i32x4*>(&L[8192 + aidx[2*p+j]]));
      }
      if (p == 0){
        #pragma unroll
        for (int nf = 0; nf < 4; ++nf){
          bh[nf]  = __builtin_bit_cast(bf16x8, *reinterpret_cast<const i32x4*>(&L[16384 + bidx[nf]]));
          bl4[nf] = __builtin_bit_cast(bf16x8, *reinterpret_cast<const i32x4*>(&L[24576 + bidx[nf]]));
        }
      }
      __builtin_amdgcn_s_barrier();
      __builtin_amdgcn_s_setprio(1);
      #pragma unroll
      for (int nf = 0; nf < 4; ++nf)
        #pragma unroll
        for (int j = 0; j < 2; ++j)
          acc[2*p+j][nf] = __builtin_amdgcn_mfma_f32_16x16x32_bf16(ah[j], bh[nf], acc[2*p+j][nf], 0, 0, 0);
      #pragma unroll
      for (int nf = 0; nf < 4; ++nf)
        #pragma unroll
        for (int j = 0; j < 2; ++j)
          acc[2*p+j][nf] = __builtin_amdgcn_mfma_f32_16x16x32_bf16(ah[j], bl4[nf], acc[2*p+j][nf], 0, 0, 0);
      #pragma unroll
      for (int nf = 0; nf < 4; ++nf)
        #pragma unroll
        for (int j = 0; j < 2; ++j)
          acc[2*p+j][nf] = __builtin_amdgcn_mfma_f32_16x16x32_bf16(al[j], bh[nf], acc[2*p+j][nf], 0, 0, 0);
      __builtin_amdgcn_s_setprio(0);
      __builtin_amdgcn_s_barrier();
    }
  }

  // epilogue: partial e over this block's 256 N-cols
  float er[32];
  #pragma unroll
  for (int j2 = 0; j2 < 32; ++j2) er[j2] = 0.0f;
  #pragma unroll
  for (int nf = 0; nf < 4; ++nf){
    int n = nb0 + (wc << 6) + (nf << 4) + l15;
    float Vl  = Vb[bb * NA + n];
    float vwl = vw[n];
    #pragma unroll
    for (int mf = 0; mf < 8; ++mf)
      #pragma unroll
      for (int i = 0; i < 4; ++i)
        er[(mf << 2) + i] += tanh_fast(acc[mf][nf][i] + Vl) * vwl;
  }
  #pragma unroll
  for (int j2 = 0; j2 < 32; ++j2){
    #pragma unroll
    for (int off = 1; off < 16; off <<= 1)
      er[j2] += __shfl_xor(er[j2], off, 64);
  }
  if (l15 == 0){
    #pragma unroll
    for (int mf = 0; mf < 8; ++mf)
      #pragma unroll
      for (int i = 0; i < 4; ++i)
        ebuf[wc][(wr << 7) + (mf << 4) + (lg << 2) + i] = er[(mf << 2) + i];
  }
  __syncthreads();
  if (t < 256)
    e_part[(size_t)nchunk * MROWS + row0 + t] =
        ebuf[0][t] + ebuf[1][t] + ebuf[2][t] + ebuf[3][t];
}

// ---------------- kernel 2 (FALLBACK): round-2 fused-convert GEMM ----------
__global__ __launch_bounds__(256) void score_fb_kernel(
    const float* __restrict__ keys,
    const unsigned short* __restrict__ Whi,
    const unsigned short* __restrict__ Wlo,
    const float* __restrict__ Vb,
    const float* __restrict__ vw,
    float* __restrict__ e_part)
{
  __shared__ __align__(16) unsigned short Ahi[128 * 64];
  __shared__ __align__(16) unsigned short Alo[128 * 64];
  __shared__ __align__(16) unsigned short Bhi[128 * 64];
  __shared__ __align__(16) unsigned short Blo[128 * 64];
  __shared__ float ebuf[4 * 64];

  const int t = threadIdx.x;
  const int w = t >> 6, l = t & 63;
  const int l15 = l & 15, lg = l >> 4;
  const int wr = w >> 1, wc = w & 1;

  const int orig = blockIdx.x;
  const int xcd = orig & 7;
  const int s = orig >> 3;
  const int mtile = ((s >> 3) << 3) | xcd;
  const int nchunk = s & 7;
  const int row0 = mtile << 7;
  const int nb0 = nchunk << 7;
  const int b = row0 >> 11;

  f32x4 acc[4][4];
  #pragma unroll
  for (int mf = 0; mf < 4; ++mf)
    #pragma unroll
    for (int nf = 0; nf < 4; ++nf)
      acc[mf][nf] = (f32x4)0.0f;

  const int arow_t = t >> 4;
  const int ak = (t & 15) << 2;
  const int ablk = ak >> 3;
  const int alow = ak & 7;

  for (int kt = 0; kt < NE / 64; ++kt){
    __syncthreads();
    f32x4 av[8];
    #pragma unroll
    for (int p = 0; p < 8; ++p){
      int row = (p << 4) + arow_t;
      av[p] = *reinterpret_cast<const f32x4*>(
          keys + (size_t)(row0 + row) * NE + (kt << 6) + ak);
    }
    #pragma unroll
    for (int c = 0; c < 4; ++c){
      const int chunk = (w << 2) + c;
      const int L = (chunk << 10) + (l << 4);
      const int brow = L >> 7;
      const int blk = ((L >> 4) & 7) ^ (brow & 7);
      const size_t goff = (size_t)(nb0 + brow) * NE + (kt << 6) + (blk << 3);
      gload_lds16(Whi + goff, &Bhi[chunk << 9]);
      gload_lds16(Wlo + goff, &Blo[chunk << 9]);
    }
    #pragma unroll
    for (int p = 0; p < 8; ++p){
      int row = (p << 4) + arow_t;
      unsigned int hp[2], lp[2];
      #pragma unroll
      for (int g = 0; g < 2; ++g){
        unsigned short h0 = f32_bf16(av[p][g * 2]);
        unsigned short h1 = f32_bf16(av[p][g * 2 + 1]);
        unsigned short l0 = f32_bf16(av[p][g * 2] - bf16_f32(h0));
        unsigned short l1 = f32_bf16(av[p][g * 2 + 1] - bf16_f32(h1));
        hp[g] = (unsigned int)h0 | ((unsigned int)h1 << 16);
        lp[g] = (unsigned int)l0 | ((unsigned int)l1 << 16);
      }
      int idx = (row << 6) + ((ablk ^ (row & 7)) << 3) + alow;
      *reinterpret_cast<u32x2*>(&Ahi[idx]) = *reinterpret_cast<u32x2*>(hp);
      *reinterpret_cast<u32x2*>(&Alo[idx]) = *reinterpret_cast<u32x2*>(lp);
    }
    __syncthreads();
    #pragma unroll
    for (int ks = 0; ks < 2; ++ks){
      bf16x8 ah[4], al4[4], bh[4], bl4[4];
      #pragma unroll
      for (int mf = 0; mf < 4; ++mf){
        int row = (wr << 6) + (mf << 4) + l15;
        int idx = (row << 6) + ((((ks << 2) + lg) ^ (row & 7)) << 3);
        ah[mf]  = __builtin_bit_cast(bf16x8, *reinterpret_cast<const i32x4*>(&Ahi[idx]));
        al4[mf] = __builtin_bit_cast(bf16x8, *reinterpret_cast<const i32x4*>(&Alo[idx]));
      }
      #pragma unroll
      for (int nf = 0; nf < 4; ++nf){
        int row = (wc << 6) + (nf << 4) + l15;
        int idx = (row << 6) + ((((ks << 2) + lg) ^ (row & 7)) << 3);
        bh[nf]  = __builtin_bit_cast(bf16x8, *reinterpret_cast<const i32x4*>(&Bhi[idx]));
        bl4[nf] = __builtin_bit_cast(bf16x8, *reinterpret_cast<const i32x4*>(&Blo[idx]));
      }
      #pragma unroll
      for (int nf = 0; nf < 4; ++nf)
        #pragma unroll
        for (int mf = 0; mf < 4; ++mf){
          acc[mf][nf] = __builtin_amdgcn_mfma_f32_16x16x32_bf16(ah[mf],  bh[nf],  acc[mf][nf], 0, 0, 0);
          acc[mf][nf] = __builtin_amdgcn_mfma_f32_16x16x32_bf16(ah[mf],  bl4[nf], acc[mf][nf], 0, 0, 0);
          acc[mf][nf] = __builtin_amdgcn_mfma_f32_16x16x32_bf16(al4[mf], bh[nf],  acc[mf][nf], 0, 0, 0);
        }
    }
  }

  float er[16];
  #pragma unroll
  for (int j = 0; j < 16; ++j) er[j] = 0.0f;
  #pragma unroll
  for (int nf = 0; nf < 4; ++nf){
    int n = nb0 + (wc << 6) + (nf << 4) + l15;
    float Vl  = Vb[b * NA + n];
    float vwl = vw[n];
    #pragma unroll
    for (int mf = 0; mf < 4; ++mf)
      #pragma unroll
      for (int i = 0; i < 4; ++i)
        er[(mf << 2) + i] += tanh_fast(acc[mf][nf][i] + Vl) * vwl;
  }
  #pragma unroll
  for (int j = 0; j < 16; ++j){
    #pragma unroll
    for (int off = 1; off < 16; off <<= 1)
      er[j] += __shfl_xor(er[j], off, 64);
  }
  if (l15 == 0){
    #pragma unroll
    for (int mf = 0; mf < 4; ++mf)
      #pragma unroll
      for (int i = 0; i < 4; ++i)
        ebuf[(w << 6) + (mf << 4) + (lg << 2) + i] = er[(mf << 2) + i];
  }
  __syncthreads();
  if (t < 128){
    int wr2 = t >> 6, r = t & 63;
    float v = ebuf[((wr2 << 1) << 6) + r] + ebuf[(((wr2 << 1) + 1) << 6) + r];
    e_part[(size_t)nchunk * MROWS + row0 + t] = v;
  }
}

// ---------------- kernel 3: sum partials + softmax over S ------------------
__global__ __launch_bounds__(256) void softmax_kernel(
    const float* __restrict__ e_part, float* __restrict__ a, int nch)
{
  __shared__ float red[4];
  const int b = blockIdx.x;
  const int t = threadIdx.x;
  const int l = t & 63, w = t >> 6;
  const float* ep = e_part + b * NS + t * 8;
  float v[8];
  #pragma unroll
  for (int j = 0; j < 8; ++j) v[j] = 0.0f;
  for (int c = 0; c < nch; ++c){
    f32x4 x0 = *reinterpret_cast<const f32x4*>(ep + (size_t)c * MROWS);
    f32x4 x1 = *reinterpret_cast<const f32x4*>(ep + (size_t)c * MROWS + 4);
    #pragma unroll
    for (int j = 0; j < 4; ++j){ v[j] += x0[j]; v[4 + j] += x1[j]; }
  }

  float m = v[0];
  #pragma unroll
  for (int j = 1; j < 8; ++j) m = fmaxf(m, v[j]);
  #pragma unroll
  for (int off = 1; off < 64; off <<= 1) m = fmaxf(m, __shfl_xor(m, off, 64));
  if (l == 0) red[w] = m;
  __syncthreads();
  m = fmaxf(fmaxf(red[0], red[1]), fmaxf(red[2], red[3]));
  __syncthreads();

  float ex[8];
  float ssum = 0.0f;
  #pragma unroll
  for (int j = 0; j < 8; ++j){ ex[j] = __expf(v[j] - m); ssum += ex[j]; }
  #pragma unroll
  for (int off = 1; off < 64; off <<= 1) ssum += __shfl_xor(ssum, off, 64);
  if (l == 0) red[w] = ssum;
  __syncthreads();
  ssum = red[0] + red[1] + red[2] + red[3];
  float inv = 1.0f / ssum;

  float o[8];
  #pragma unroll
  for (int j = 0; j < 8; ++j) o[j] = ex[j] * inv;
  float* ap = a + b * NS + t * 8;
  *reinterpret_cast<f32x4*>(ap)     = *reinterpret_cast<f32x4*>(&o[0]);
  *reinterpret_cast<f32x4*>(ap + 4) = *reinterpret_cast<f32x4*>(&o[4]);
}

// ---------------- kernel 4a: partial context (f32 keys, fallback) ----------
__global__ __launch_bounds__(256) void ctx_partial_kernel(
    const float* __restrict__ a, const float* __restrict__ keys,
    float* __restrict__ part)
{
  const int bid = blockIdx.x;
  const int b = bid >> 3, sc = bid & 7;
  const int t = threadIdx.x;
  f32x4 accv = (f32x4)0.0f;
  const float* kp = keys + (size_t)(b * NS + sc * 256) * NE + t * 4;
  const float* ap = a + b * NS + sc * 256;
  for (int si = 0; si < 256; ++si){
    float as = ap[si];
    f32x4 k4 = *reinterpret_cast<const f32x4*>(kp + (size_t)si * NE);
    accv += as * k4;
  }
  *reinterpret_cast<f32x4*>(part + (size_t)bid * NE + t * 4) = accv;
}

// ---------------- kernel 4a' : partial context (bf16-hi keys, big) ---------
__global__ __launch_bounds__(256) void ctx_partial_bf16_kernel(
    const float* __restrict__ a, const unsigned short* __restrict__ khi,
    float* __restrict__ part)
{
  const int bid = blockIdx.x;
  const int b = bid >> 3, sc = bid & 7;
  const int t = threadIdx.x;
  f32x4 accv = (f32x4)0.0f;
  const unsigned short* kp = khi + (size_t)(b * NS + sc * 256) * NE + t * 4;
  const float* ap = a + b * NS + sc * 256;
  for (int si = 0; si < 256; ++si){
    float as = ap[si];
    u16x4 k4 = *reinterpret_cast<const u16x4*>(kp + (size_t)si * NE);
    #pragma unroll
    for (int j = 0; j < 4; ++j) accv[j] += as * bf16_f32(k4[j]);
  }
  *reinterpret_cast<f32x4*>(part + (size_t)bid * NE + t * 4) = accv;
}

// ---------------- kernel 4b: deterministic reduce of partials --------------
__global__ __launch_bounds__(256) void ctx_reduce_kernel(
    const float* __restrict__ part, float* __restrict__ out)
{
  const int b = blockIdx.x;
  const int t = threadIdx.x;
  f32x4 s = (f32x4)0.0f;
  #pragma unroll
  for (int sc = 0; sc < 8; ++sc)
    s += *reinterpret_cast<const f32x4*>(part + (size_t)((b << 3) + sc) * NE + t * 4);
  *reinterpret_cast<f32x4*>(out + b * NE + t * 4) = s;
}

extern "C" void kernel_launch(void* const* d_in, const int* in_sizes, int n_in,
                              void* d_out, int out_size, void* d_ws, size_t ws_size,
                              hipStream_t stream)
{
  const float* keys = (const float*)d_in[0];
  const float* q    = (const float*)d_in[1];
  const float* We   = (const float*)d_in[2];
  const float* Wd   = (const float*)d_in[3];
  const float* vw   = (const float*)d_in[4];
  float* out = (float*)d_out;

  char* ws = (char*)d_ws;
  const size_t MB = 1024 * 1024;
  unsigned short* Whi = (unsigned short*)(ws);            // 2 MB
  unsigned short* Wlo = (unsigned short*)(ws + 2 * MB);   // 2 MB
  float* Vb     = (float*)(ws + 4 * MB);                  // 128 KB
  float* e_part = (float*)(ws + 4 * MB + 131072);         // up to 2 MB
  float* a      = (float*)(ws + 6 * MB + 131072);         // 256 KB
  float* part   = e_part;  // aliased: e_part dead after softmax

  const bool big = ws_size >= 264 * MB;

  split_w_kernel<<<(NA * NE) / 1024, 256, 0, stream>>>(We, Whi, Wlo);
  v_kernel<<<(NB * NA) / 4, 256, 0, stream>>>(q, Wd, Vb);

  if (big){
    unsigned short* Khi = (unsigned short*)(ws + 8 * MB);    // 128 MB
    unsigned short* Klo = (unsigned short*)(ws + 136 * MB);  // 128 MB
    split_keys_kernel<<<(MROWS * (size_t)NE) / 2048, 256, 0, stream>>>(keys, Khi, Klo);
    score_big_kernel<<<1024, 512, 0, stream>>>(Khi, Klo, Whi, Wlo, Vb, vw, e_part);
    softmax_kernel<<<NB, 256, 0, stream>>>(e_part, a, 4);
    ctx_partial_bf16_kernel<<<NB * 8, 256, 0, stream>>>(a, Khi, part);
  } else {
    score_fb_kernel<<<4096, 256, 0, stream>>>(keys, Whi, Wlo, Vb, vw, e_part);
    softmax_kernel<<<NB, 256, 0, stream>>>(e_part, a, 8);
    ctx_partial_kernel<<<NB * 8, 256, 0, stream>>>(a, keys, part);
  }
  ctx_reduce_kernel<<<NB, 256, 0, stream>>>(part, out);
}